// Round 12
// baseline (97.317 us; speedup 1.0000x reference)
//
#include <hip/hip_runtime.h>
#include <hip/hip_fp16.h>

typedef __attribute__((ext_vector_type(8)))  _Float16 half8;
typedef __attribute__((ext_vector_type(16))) float    f32x16;

#define B_   16
#define NPTS 4096                      // points per batch (N == M == 4096)

constexpr int BLK   = 256;             // 4 waves
constexpr int WV    = 4;
constexpr int QPW   = 32;              // queries per wave (MFMA N-dim)
constexpr int QPB   = WV * QPW;        // 128 queries per block
constexpr int NQC   = NPTS / QPB;      // 32 query chunks
constexpr int NIT   = NPTS / 64;       // 64 iterations (64 targets each)
constexpr int NBLK  = 2 * B_ * NQC;    // 1024 blocks
constexpr int HALF  = B_ * NPTS;       // points per direction

__device__ __forceinline__ float min3f(float a, float b, float c) {
    return fminf(fminf(a, b), c);      // -> v_min3_f32
}

// ------------------------------------------------------------------
// prep: build the A-fragment row for every target point of both
// directions: arow[dir*HALF + b*NPTS + j] = [-2x,-2y,-2z,g2hi,g2lo,0,0,0]
// (fp16, |g|^2 split hi+lo for exactness -- verified lineage R7-R11).
__global__ void prep_kernel(const float* __restrict__ pred,
                            const float* __restrict__ gt,
                            uint4* __restrict__ arow) {
    int i = blockIdx.x * blockDim.x + threadIdx.x;   // [0, 2*HALF)
    const float* src = (i < HALF) ? gt : pred;       // dir0 targets = gt
    int j = (i < HALF) ? i : i - HALF;
    __half hx = __float2half(src[3 * j + 0]);
    __half hy = __float2half(src[3 * j + 1]);
    __half hz = __float2half(src[3 * j + 2]);
    float fx = __half2float(hx), fy = __half2float(hy), fz = __half2float(hz);
    float g2 = fmaf(fx, fx, fmaf(fy, fy, fz * fz));
    __half ax = __float2half(-2.0f * fx);
    __half ay = __float2half(-2.0f * fy);
    __half az = __float2half(-2.0f * fz);
    __half g2hi = __float2half(g2);
    __half g2lo = __float2half(g2 - __half2float(g2hi));
    uint4 w;
    w.x = (unsigned)__half_as_ushort(ax) | ((unsigned)__half_as_ushort(ay) << 16);
    w.y = (unsigned)__half_as_ushort(az) | ((unsigned)__half_as_ushort(g2hi) << 16);
    w.z = (unsigned)__half_as_ushort(g2lo);
    w.w = 0u;
    arow[i] = w;
}

// ------------------------------------------------------------------
// main: block = (dir, b, 128-query chunk); NO LDS staging, NO loop
// barriers -- waves free-run over all 4096 targets so pipes de-phase.
// Per iteration: ONE global_load_dwordx4 (lane L = tile-even row L,
// lane L+32 = tile-odd row L) + TWO MFMAs with K-half-split B-frags
// (bL: query data only in lanes<32 -> contracts tile-even; bH: lanes>=32
// -> tile-odd; the zero half annihilates the other tile) + 16 min3.
// D = |g|^2 - 2 q.g exactly (no K-duplication), d^2 = minD + |q|^2
// with q from the SAME fp16-rounded coords (exact perturbed metric).
__global__ __launch_bounds__(BLK, 4) void chamfer_main(
        const float* __restrict__ pred, const float* __restrict__ gt,
        const uint4* __restrict__ arow,
        float* __restrict__ accum, unsigned* __restrict__ counter,
        float* __restrict__ out) {
    const int qc  = blockIdx.x;
    const int b   = blockIdx.y;
    const int dir = blockIdx.z;
    const float* qsrc = dir ? gt : pred;     // queries

    __shared__ float ps[WV];

    const int tid  = threadIdx.x;
    const int lane = tid & 63;
    const int wv   = tid >> 6;
    const int m    = lane & 31;

    // ---- B fragments: this lane's query, K-half split ----
    const float* qp = qsrc + (b * NPTS + qc * QPB + wv * QPW + m) * 3;
    __half hqx = __float2half(qp[0]);
    __half hqy = __float2half(qp[1]);
    __half hqz = __float2half(qp[2]);
    float fqx = __half2float(hqx), fqy = __half2float(hqy), fqz = __half2float(hqz);
    const float q2 = fmaf(fqx, fqx, fmaf(fqy, fqy, fqz * fqz));
    uint4 bu;
    bu.x = (unsigned)__half_as_ushort(hqx) | ((unsigned)__half_as_ushort(hqy) << 16);
    bu.y = (unsigned)__half_as_ushort(hqz) | (0x3C00u << 16);   // {z, 1.0}
    bu.z = 0x3C00u;                                             // {1.0, 0}
    bu.w = 0u;
    const uint4 zu = make_uint4(0u, 0u, 0u, 0u);
    const bool lo = (lane < 32);
    uint4 bLu, bHu;
    bLu.x = lo ? bu.x : 0u; bLu.y = lo ? bu.y : 0u;
    bLu.z = lo ? bu.z : 0u; bLu.w = 0u;
    bHu.x = lo ? 0u : bu.x; bHu.y = lo ? 0u : bu.y;
    bHu.z = lo ? 0u : bu.z; bHu.w = 0u;
    const half8 bL = __builtin_bit_cast(half8, bLu);
    const half8 bH = __builtin_bit_cast(half8, bHu);

    f32x16 zero;
#pragma unroll
    for (int i = 0; i < 16; ++i) zero[i] = 0.0f;
    f32x16 mn;
#pragma unroll
    for (int i = 0; i < 16; ++i) mn[i] = 1e30f;

    // ---- sweep all targets: 64 per iteration, no barriers ----
    const uint4* ap = arow + dir * HALF + b * NPTS + lane;
#pragma unroll 4
    for (int it = 0; it < NIT; ++it) {
        uint4 au = ap[it * 64];              // global_load_dwordx4 (L2-hot)
        half8 a = __builtin_bit_cast(half8, au);
        f32x16 d0 = __builtin_amdgcn_mfma_f32_32x32x16_f16(a, bL, zero, 0, 0, 0);
        f32x16 d1 = __builtin_amdgcn_mfma_f32_32x32x16_f16(a, bH, zero, 0, 0, 0);
#pragma unroll
        for (int i = 0; i < 16; ++i)
            mn[i] = min3f(mn[i], d0[i], d1[i]);   // 16 indep chains
    }

    // ---- final fold: tree over 16 regs, then lane^32 row-half merge ----
    float a0 = min3f(mn[0],  mn[1],  mn[2]);
    float a1 = min3f(mn[3],  mn[4],  mn[5]);
    float a2 = min3f(mn[6],  mn[7],  mn[8]);
    float a3 = min3f(mn[9],  mn[10], mn[11]);
    float a4 = min3f(mn[12], mn[13], mn[14]);
    float v  = fminf(min3f(a0, a1, a2), min3f(a3, a4, mn[15]));
    v = fminf(v, __shfl_xor(v, 32));

    float dd = fmaxf(v + q2, 0.0f);          // no 0.5: K not duplicated
    float s  = sqrtf(dd);
#pragma unroll
    for (int off = 32; off; off >>= 1) s += __shfl_xor(s, off);
    if (lane == 0) ps[wv] = 0.5f * s;        // each query counted twice
    __syncthreads();

    if (tid == 0) {
        atomicAdd(accum, ps[0] + ps[1] + ps[2] + ps[3]);
        __threadfence();
        if (atomicAdd(counter, 1u) == NBLK - 1) {   // last block finalizes
            float total = atomicAdd(accum, 0.0f);   // coherent read
            float loss  = total * (1.0f / (float)(B_ * NPTS));
            out[0] = loss;          // WEIGHT * loss, WEIGHT = 1
            out[1] = loss;          // helper_loss
            out[2] = 0.1f * loss;   // helper_cderr = p1 chamfer * xyz_unit
        }
    }
}

// ------------------------------------------------------------------
extern "C" void kernel_launch(void* const* d_in, const int* in_sizes, int n_in,
                              void* d_out, int out_size, void* d_ws, size_t ws_size,
                              hipStream_t stream) {
    const float* pred = (const float*)d_in[0];
    const float* gt   = (const float*)d_in[1];
    float* out = (float*)d_out;

    float*    accum   = (float*)d_ws;
    unsigned* counter = (unsigned*)d_ws + 1;
    uint4*    arow    = (uint4*)((char*)d_ws + 1024);   // 2 MB A-row array

    hipMemsetAsync(d_ws, 0, 8, stream);
    prep_kernel<<<dim3(2 * HALF / 256), 256, 0, stream>>>(pred, gt, arow);
    chamfer_main<<<dim3(NQC, B_, 2), BLK, 0, stream>>>(pred, gt, arow,
                                                       accum, counter, out);
}